// Round 1
// baseline (151.790 us; speedup 1.0000x reference)
//
#include <hip/hip_runtime.h>
#include <math.h>

#define SPW 4          // samples per wave
#define WAVES_PER_BLOCK 4

__device__ __forceinline__ float wave_bcast_sum(float v) {
#pragma unroll
    for (int m = 1; m < 64; m <<= 1) v += __shfl_xor(v, m, 64);
    return v;
}

__global__ __launch_bounds__(256) void hybridqrc_kernel(
    const float* __restrict__ xs,  const float* __restrict__ xl,
    const float* __restrict__ csw, const float* __restrict__ csb,
    const float* __restrict__ lsw, const float* __restrict__ lsb,
    const float* __restrict__ clw, const float* __restrict__ clb,
    const float* __restrict__ llw, const float* __restrict__ llb,
    const float* __restrict__ qw,  const float* __restrict__ fc1w,
    const float* __restrict__ fc1b,const float* __restrict__ fc2w,
    const float* __restrict__ fc2b,float* __restrict__ out, int B)
{
    // ---- per-block: precompute the 12 Rot gate matrices (sample-independent) ----
    // gate (l*6+j): [g00r,g00i, g01r,g01i, g10r,g10i, g11r,g11i]
    __shared__ float gme[12 * 8];
    const int tid = threadIdx.x;
    if (tid < 12) {
        float phi = qw[tid * 3 + 0], th = qw[tid * 3 + 1], om = qw[tid * 3 + 2];
        float a = 0.5f * (phi + om), b = 0.5f * (phi - om);
        float ca = cosf(a), sa = sinf(a);
        float cb = cosf(b), sb = sinf(b);
        float ct = cosf(0.5f * th), st = sinf(0.5f * th);
        // Rot = RZ(om) RY(th) RZ(phi):
        // g00 = e^{-ia} ct ; g01 = -e^{+ib} st ; g10 = e^{-ib} st ; g11 = e^{+ia} ct
        gme[tid * 8 + 0] =  ca * ct;  gme[tid * 8 + 1] = -sa * ct;
        gme[tid * 8 + 2] = -cb * st;  gme[tid * 8 + 3] = -sb * st;
        gme[tid * 8 + 4] =  cb * st;  gme[tid * 8 + 5] = -sb * st;
        gme[tid * 8 + 6] =  ca * ct;  gme[tid * 8 + 7] =  sa * ct;
    }
    __syncthreads();

    const int lane = tid & 63;
    const int wave = blockIdx.x * WAVES_PER_BLOCK + (tid >> 6);
    const int base = wave * SPW;
    if (base >= B) return;

    // ---- classical branches: accumulate combined (short+long) linear sums ----
    float acc[SPW][6];
#pragma unroll
    for (int i = 0; i < SPW; i++)
#pragma unroll
        for (int q = 0; q < 6; q++) acc[i][q] = 0.f;

    // short branch: lane = position w in [0,64)
    float xsv[SPW], xm1[SPW], xp1[SPW];
#pragma unroll
    for (int i = 0; i < SPW; i++) xsv[i] = xs[(base + i) * 64 + lane];
#pragma unroll
    for (int i = 0; i < SPW; i++) {
        float lft = __shfl(xsv[i], (lane + 63) & 63, 64);
        float rgt = __shfl(xsv[i], (lane + 1) & 63, 64);
        xm1[i] = (lane == 0)  ? 0.f : lft;
        xp1[i] = (lane == 63) ? 0.f : rgt;
    }
#pragma unroll
    for (int c = 0; c < 16; c++) {
        float w0 = csw[c * 3 + 0], w1 = csw[c * 3 + 1], w2 = csw[c * 3 + 2];
        float bb = csb[c];
        float h[SPW];
#pragma unroll
        for (int i = 0; i < SPW; i++)
            h[i] = fmaxf(0.f, fmaf(w0, xm1[i], fmaf(w1, xsv[i], fmaf(w2, xp1[i], bb))));
#pragma unroll
        for (int q = 0; q < 6; q++) {
            float wv = lsw[q * 1024 + c * 64 + lane];
#pragma unroll
            for (int i = 0; i < SPW; i++) acc[i][q] = fmaf(h[i], wv, acc[i][q]);
        }
    }

    // long branch: lane owns positions lane*4 .. lane*4+3
    float4 xlv[SPW];
    float l2v[SPW], l1v[SPW], r1v[SPW], r2v[SPW];
#pragma unroll
    for (int i = 0; i < SPW; i++)
        xlv[i] = reinterpret_cast<const float4*>(xl + (size_t)(base + i) * 256)[lane];
#pragma unroll
    for (int i = 0; i < SPW; i++) {
        float a = __shfl(xlv[i].z, (lane + 63) & 63, 64);
        float b = __shfl(xlv[i].w, (lane + 63) & 63, 64);
        float c = __shfl(xlv[i].x, (lane + 1) & 63, 64);
        float d = __shfl(xlv[i].y, (lane + 1) & 63, 64);
        l2v[i] = (lane == 0)  ? 0.f : a;
        l1v[i] = (lane == 0)  ? 0.f : b;
        r1v[i] = (lane == 63) ? 0.f : c;
        r2v[i] = (lane == 63) ? 0.f : d;
    }
#pragma unroll
    for (int c = 0; c < 16; c++) {
        float w0 = clw[c * 5 + 0], w1 = clw[c * 5 + 1], w2 = clw[c * 5 + 2];
        float w3 = clw[c * 5 + 3], w4 = clw[c * 5 + 4];
        float bb = clb[c];
        float p0[SPW], p1[SPW];
#pragma unroll
        for (int i = 0; i < SPW; i++) {
            float vx = xlv[i].x, vy = xlv[i].y, vz = xlv[i].z, vw = xlv[i].w;
            float h0 = fmaf(w0, l2v[i], fmaf(w1, l1v[i], fmaf(w2, vx, fmaf(w3, vy, fmaf(w4, vz, bb)))));
            float h1 = fmaf(w0, l1v[i], fmaf(w1, vx, fmaf(w2, vy, fmaf(w3, vz, fmaf(w4, vw, bb)))));
            float h2 = fmaf(w0, vx, fmaf(w1, vy, fmaf(w2, vz, fmaf(w3, vw, fmaf(w4, r1v[i], bb)))));
            float h3 = fmaf(w0, vy, fmaf(w1, vz, fmaf(w2, vw, fmaf(w3, r1v[i], fmaf(w4, r2v[i], bb)))));
            h0 = fmaxf(h0, 0.f); h1 = fmaxf(h1, 0.f);
            h2 = fmaxf(h2, 0.f); h3 = fmaxf(h3, 0.f);
            p0[i] = fmaxf(h0, h1);
            p1[i] = fmaxf(h2, h3);
        }
#pragma unroll
        for (int q = 0; q < 6; q++) {
            float2 wv = reinterpret_cast<const float2*>(llw + q * 2048 + c * 128)[lane];
#pragma unroll
            for (int i = 0; i < SPW; i++)
                acc[i][q] = fmaf(p0[i], wv.x, fmaf(p1[i], wv.y, acc[i][q]));
        }
    }

    // f = (fs + fl)/2 ; biases added once after the wave reduction
    float f[SPW][6];
#pragma unroll
    for (int i = 0; i < SPW; i++)
#pragma unroll
        for (int q = 0; q < 6; q++)
            f[i][q] = 0.5f * (wave_bcast_sum(acc[i][q]) + lsb[q] + llb[q]);

    // ---- quantum circuit: 64 amplitudes == 64 lanes (wire j <-> bit 5-j) ----
    float outv[SPW];
#pragma unroll
    for (int i = 0; i < SPW; i++) {
        // RY(pi*f) encoding of |0..0> -> real product state
        float ar = 1.f, ai = 0.f;
#pragma unroll
        for (int j = 0; j < 6; j++) {
            float th = 0.5f * 3.14159265358979323846f * f[i][j];
            float ss, cc;
            sincosf(th, &ss, &cc);
            int bit = (lane >> (5 - j)) & 1;
            ar *= bit ? ss : cc;
        }
#pragma unroll
        for (int l = 0; l < 2; l++) {
#pragma unroll
            for (int j = 0; j < 6; j++) {
                const float* g = &gme[(l * 6 + j) * 8];
                const int mask = 1 << (5 - j);
                int bit = (lane >> (5 - j)) & 1;
                float br = __shfl_xor(ar, mask, 64);
                float bi = __shfl_xor(ai, mask, 64);
                // own-coeff: bit? g11 : g00 ; other-coeff: bit? g10 : g01
                float c0r = bit ? g[6] : g[0], c0i = bit ? g[7] : g[1];
                float c1r = bit ? g[4] : g[2], c1i = bit ? g[5] : g[3];
                float nr = c0r * ar - c0i * ai + c1r * br - c1i * bi;
                float ni = c0r * ai + c0i * ar + c1r * bi + c1i * br;
                ar = nr; ai = ni;
            }
            const int r = (l % 5) + 1;  // l % (n-1) + 1
#pragma unroll
            for (int j = 0; j < 6; j++) {
                const int t = (j + r) % 6;
                const int cm = 1 << (5 - j), tm = 1 << (5 - t);
                float br = __shfl_xor(ar, tm, 64);
                float bi = __shfl_xor(ai, tm, 64);
                bool ctl = (lane & cm) != 0;
                ar = ctl ? br : ar;
                ai = ctl ? bi : ai;
            }
        }
        // <Z_k> from |amp|^2
        float p = ar * ar + ai * ai;
        float z[6];
#pragma unroll
        for (int k = 0; k < 6; k++) {
            float sgn = ((lane >> (5 - k)) & 1) ? -1.f : 1.f;
            z[k] = wave_bcast_sum(p * sgn);
        }
        // fc head (uniform, computed redundantly per lane)
        float o = fc2b[0];
#pragma unroll
        for (int m = 0; m < 8; m++) {
            float h = fc1b[m];
#pragma unroll
            for (int k = 0; k < 6; k++) h = fmaf(fc1w[m * 6 + k], z[k], h);
            h = fmaxf(h, 0.f);
            o = fmaf(fc2w[m], h, o);
        }
        outv[i] = o;
    }

    if (lane == 0) {
#pragma unroll
        for (int i = 0; i < SPW; i++)
            if (base + i < B) out[base + i] = outv[i];
    }
}

extern "C" void kernel_launch(void* const* d_in, const int* in_sizes, int n_in,
                              void* d_out, int out_size, void* d_ws, size_t ws_size,
                              hipStream_t stream) {
    const float* xs   = (const float*)d_in[0];
    const float* xl   = (const float*)d_in[1];
    const float* csw  = (const float*)d_in[2];
    const float* csb  = (const float*)d_in[3];
    const float* lsw  = (const float*)d_in[4];
    const float* lsb  = (const float*)d_in[5];
    const float* clw  = (const float*)d_in[6];
    const float* clb  = (const float*)d_in[7];
    const float* llw  = (const float*)d_in[8];
    const float* llb  = (const float*)d_in[9];
    const float* qw   = (const float*)d_in[10];
    const float* fc1w = (const float*)d_in[11];
    const float* fc1b = (const float*)d_in[12];
    const float* fc2w = (const float*)d_in[13];
    const float* fc2b = (const float*)d_in[14];
    float* out = (float*)d_out;

    const int B = in_sizes[0] / 64;
    const int waves = (B + SPW - 1) / SPW;
    const int blocks = (waves + WAVES_PER_BLOCK - 1) / WAVES_PER_BLOCK;
    hybridqrc_kernel<<<blocks, 256, 0, stream>>>(
        xs, xl, csw, csb, lsw, lsb, clw, clb, llw, llb,
        qw, fc1w, fc1b, fc2w, fc2b, out, B);
}

// Round 2
// 126.259 us; speedup vs baseline: 1.2022x; 1.2022x over previous
//
#include <hip/hip_runtime.h>
#include <math.h>

#define SPW 2          // samples per wave
#define WAVES_PER_BLOCK 4

__device__ __forceinline__ float wave_bcast_sum(float v) {
#pragma unroll
    for (int m = 1; m < 64; m <<= 1) v += __shfl_xor(v, m, 64);
    return v;
}

__global__ __launch_bounds__(256) void hybridqrc_kernel(
    const float* __restrict__ xs,  const float* __restrict__ xl,
    const float* __restrict__ csw, const float* __restrict__ csb,
    const float* __restrict__ lsw, const float* __restrict__ lsb,
    const float* __restrict__ clw, const float* __restrict__ clb,
    const float* __restrict__ llw, const float* __restrict__ llb,
    const float* __restrict__ qw,  const float* __restrict__ fc1w,
    const float* __restrict__ fc1b,const float* __restrict__ fc2w,
    const float* __restrict__ fc2b,float* __restrict__ out, int B)
{
    // ---- per-block: 12 Rot gates, pre-selected per target-bit ----
    // gme[gate*2+bit] = (own_r, own_i, oth_r, oth_i)
    //   bit=0: own=g00=e^{-ia}ct, oth=g01=-e^{+ib}st
    //   bit=1: own=g11=e^{+ia}ct, oth=g10=e^{-ib}st
    __shared__ float4 gme[24];
    const int tid = threadIdx.x;
    if (tid < 24) {
        int g = tid >> 1, bit = tid & 1;
        float phi = qw[g * 3 + 0], th = qw[g * 3 + 1], om = qw[g * 3 + 2];
        float a = 0.5f * (phi + om), b = 0.5f * (phi - om);
        float ca = cosf(a), sa = sinf(a);
        float cb = cosf(b), sb = sinf(b);
        float ct = cosf(0.5f * th), st = sinf(0.5f * th);
        float4 v;
        if (bit) { v.x = ca * ct; v.y =  sa * ct; v.z =  cb * st; v.w = -sb * st; }
        else     { v.x = ca * ct; v.y = -sa * ct; v.z = -cb * st; v.w = -sb * st; }
        gme[tid] = v;
    }
    __syncthreads();

    const int lane = tid & 63;
    const int wave = blockIdx.x * WAVES_PER_BLOCK + (tid >> 6);
    const int base = wave * SPW;
    if (base >= B) return;

    // ---- fused CNOT-ring permutations (lane-only, sample-independent) ----
    // layer l: r = l%5+1; CNOT j->(j+r)%6 applied j=0..5; src(x) = s0(s1(..s5(x)))
    int perm0, perm1;
    {
        int y = lane;
#pragma unroll
        for (int j = 5; j >= 0; j--) {
            const int t = (j + 1) % 6;
            const int cm = 1 << (5 - j), tm = 1 << (5 - t);
            y ^= (y & cm) ? tm : 0;
        }
        perm0 = y;
        y = lane;
#pragma unroll
        for (int j = 5; j >= 0; j--) {
            const int t = (j + 2) % 6;
            const int cm = 1 << (5 - j), tm = 1 << (5 - t);
            y ^= (y & cm) ? tm : 0;
        }
        perm1 = y;
    }

    // ---- classical branches: accumulate combined (short+long) linear sums ----
    float acc[SPW][6];
#pragma unroll
    for (int i = 0; i < SPW; i++)
#pragma unroll
        for (int q = 0; q < 6; q++) acc[i][q] = 0.f;

    // short branch: lane = position w in [0,64)
    float xsv[SPW], xm1[SPW], xp1[SPW];
#pragma unroll
    for (int i = 0; i < SPW; i++) xsv[i] = xs[(base + i) * 64 + lane];
#pragma unroll
    for (int i = 0; i < SPW; i++) {
        float lft = __shfl(xsv[i], (lane + 63) & 63, 64);
        float rgt = __shfl(xsv[i], (lane + 1) & 63, 64);
        xm1[i] = (lane == 0)  ? 0.f : lft;
        xp1[i] = (lane == 63) ? 0.f : rgt;
    }
#pragma unroll
    for (int c = 0; c < 16; c++) {
        float w0 = csw[c * 3 + 0], w1 = csw[c * 3 + 1], w2 = csw[c * 3 + 2];
        float bb = csb[c];
        float h[SPW];
#pragma unroll
        for (int i = 0; i < SPW; i++)
            h[i] = fmaxf(0.f, fmaf(w0, xm1[i], fmaf(w1, xsv[i], fmaf(w2, xp1[i], bb))));
#pragma unroll
        for (int q = 0; q < 6; q++) {
            float wv = lsw[q * 1024 + c * 64 + lane];
#pragma unroll
            for (int i = 0; i < SPW; i++) acc[i][q] = fmaf(h[i], wv, acc[i][q]);
        }
    }

    // long branch: lane owns positions lane*4 .. lane*4+3
    float4 xlv[SPW];
    float l2v[SPW], l1v[SPW], r1v[SPW], r2v[SPW];
#pragma unroll
    for (int i = 0; i < SPW; i++)
        xlv[i] = reinterpret_cast<const float4*>(xl + (size_t)(base + i) * 256)[lane];
#pragma unroll
    for (int i = 0; i < SPW; i++) {
        float a = __shfl(xlv[i].z, (lane + 63) & 63, 64);
        float b = __shfl(xlv[i].w, (lane + 63) & 63, 64);
        float c = __shfl(xlv[i].x, (lane + 1) & 63, 64);
        float d = __shfl(xlv[i].y, (lane + 1) & 63, 64);
        l2v[i] = (lane == 0)  ? 0.f : a;
        l1v[i] = (lane == 0)  ? 0.f : b;
        r1v[i] = (lane == 63) ? 0.f : c;
        r2v[i] = (lane == 63) ? 0.f : d;
    }
#pragma unroll
    for (int c = 0; c < 16; c++) {
        float w0 = clw[c * 5 + 0], w1 = clw[c * 5 + 1], w2 = clw[c * 5 + 2];
        float w3 = clw[c * 5 + 3], w4 = clw[c * 5 + 4];
        float bb = clb[c];
        float p0[SPW], p1[SPW];
#pragma unroll
        for (int i = 0; i < SPW; i++) {
            float vx = xlv[i].x, vy = xlv[i].y, vz = xlv[i].z, vw = xlv[i].w;
            float h0 = fmaf(w0, l2v[i], fmaf(w1, l1v[i], fmaf(w2, vx, fmaf(w3, vy, fmaf(w4, vz, bb)))));
            float h1 = fmaf(w0, l1v[i], fmaf(w1, vx, fmaf(w2, vy, fmaf(w3, vz, fmaf(w4, vw, bb)))));
            float h2 = fmaf(w0, vx, fmaf(w1, vy, fmaf(w2, vz, fmaf(w3, vw, fmaf(w4, r1v[i], bb)))));
            float h3 = fmaf(w0, vy, fmaf(w1, vz, fmaf(w2, vw, fmaf(w3, r1v[i], fmaf(w4, r2v[i], bb)))));
            h0 = fmaxf(h0, 0.f); h1 = fmaxf(h1, 0.f);
            h2 = fmaxf(h2, 0.f); h3 = fmaxf(h3, 0.f);
            p0[i] = fmaxf(h0, h1);
            p1[i] = fmaxf(h2, h3);
        }
#pragma unroll
        for (int q = 0; q < 6; q++) {
            float2 wv = reinterpret_cast<const float2*>(llw + q * 2048 + c * 128)[lane];
#pragma unroll
            for (int i = 0; i < SPW; i++)
                acc[i][q] = fmaf(p0[i], wv.x, fmaf(p1[i], wv.y, acc[i][q]));
        }
    }

    // f = (fs + fl)/2 ; biases added once after the wave reduction
    float f[SPW][6];
#pragma unroll
    for (int i = 0; i < SPW; i++)
#pragma unroll
        for (int q = 0; q < 6; q++)
            f[i][q] = 0.5f * (wave_bcast_sum(acc[i][q]) + lsb[q] + llb[q]);

    // ---- quantum circuit: 64 amplitudes == 64 lanes (wire j <-> bit 5-j) ----
    float outv[SPW];
#pragma unroll
    for (int i = 0; i < SPW; i++) {
        // RY(pi*f) encoding of |0..0> -> real product state (native sin/cos)
        float ar = 1.f, ai = 0.f;
#pragma unroll
        for (int j = 0; j < 6; j++) {
            float th = 1.57079632679489662f * f[i][j];
            float ss = __sinf(th), cc = __cosf(th);
            ar *= ((lane >> (5 - j)) & 1) ? ss : cc;
        }
#pragma unroll
        for (int l = 0; l < 2; l++) {
#pragma unroll
            for (int j = 0; j < 6; j++) {
                const int mask = 1 << (5 - j);
                const int bit = (lane & mask) ? 1 : 0;
                float4 g = gme[(l * 6 + j) * 2 + bit];
                float br = __shfl_xor(ar, mask, 64);
                float bi = __shfl_xor(ai, mask, 64);
                float nr = g.x * ar - g.y * ai + g.z * br - g.w * bi;
                float ni = g.x * ai + g.y * ar + g.z * bi + g.w * br;
                ar = nr; ai = ni;
            }
            // fused CNOT ring: single arbitrary-permutation shuffle
            const int p = l ? perm1 : perm0;
            float pr = __shfl(ar, p, 64);
            float pi2 = __shfl(ai, p, 64);
            ar = pr; ai = pi2;
        }
        // all six <Z_k> via one Walsh-Hadamard butterfly; z[k] in lane 1<<(5-k)
        float v = ar * ar + ai * ai;
#pragma unroll
        for (int m = 1; m < 64; m <<= 1) {
            float pp = __shfl_xor(v, m, 64);
            v = (lane & m) ? (pp - v) : (v + pp);
        }
        float z[6];
#pragma unroll
        for (int k = 0; k < 6; k++) z[k] = __shfl(v, 1 << (5 - k), 64);
        // fc head (uniform, computed redundantly per lane)
        float o = fc2b[0];
#pragma unroll
        for (int m = 0; m < 8; m++) {
            float h = fc1b[m];
#pragma unroll
            for (int k = 0; k < 6; k++) h = fmaf(fc1w[m * 6 + k], z[k], h);
            h = fmaxf(h, 0.f);
            o = fmaf(fc2w[m], h, o);
        }
        outv[i] = o;
    }

    if (lane == 0) {
#pragma unroll
        for (int i = 0; i < SPW; i++)
            if (base + i < B) out[base + i] = outv[i];
    }
}

extern "C" void kernel_launch(void* const* d_in, const int* in_sizes, int n_in,
                              void* d_out, int out_size, void* d_ws, size_t ws_size,
                              hipStream_t stream) {
    const float* xs   = (const float*)d_in[0];
    const float* xl   = (const float*)d_in[1];
    const float* csw  = (const float*)d_in[2];
    const float* csb  = (const float*)d_in[3];
    const float* lsw  = (const float*)d_in[4];
    const float* lsb  = (const float*)d_in[5];
    const float* clw  = (const float*)d_in[6];
    const float* clb  = (const float*)d_in[7];
    const float* llw  = (const float*)d_in[8];
    const float* llb  = (const float*)d_in[9];
    const float* qw   = (const float*)d_in[10];
    const float* fc1w = (const float*)d_in[11];
    const float* fc1b = (const float*)d_in[12];
    const float* fc2w = (const float*)d_in[13];
    const float* fc2b = (const float*)d_in[14];
    float* out = (float*)d_out;

    const int B = in_sizes[0] / 64;
    const int waves = (B + SPW - 1) / SPW;
    const int blocks = (waves + WAVES_PER_BLOCK - 1) / WAVES_PER_BLOCK;
    hybridqrc_kernel<<<blocks, 256, 0, stream>>>(
        xs, xl, csw, csb, lsw, lsb, clw, clb, llw, llb,
        qw, fc1w, fc1b, fc2w, fc2b, out, B);
}

// Round 4
// 123.719 us; speedup vs baseline: 1.2269x; 1.0205x over previous
//
#include <hip/hip_runtime.h>
#include <math.h>

#define SPW 2          // samples per wave
#define WAVES_PER_BLOCK 4

#define DPPQ(a,b,c,d) ((a)|((b)<<2)|((c)<<4)|((d)<<6))
#define DPP_XOR1 DPPQ(1,0,3,2)
#define DPP_XOR2 DPPQ(2,3,0,1)
#define DPP_MIR7 0x141   // row_half_mirror  = lane ^ 7  (within 16-lane row)
#define DPP_MIR15 0x140  // row_mirror       = lane ^ 15

template<int CTRL>
__device__ __forceinline__ float dppf(float v) {
    return __int_as_float(__builtin_amdgcn_update_dpp(
        0, __float_as_int(v), CTRL, 0xF, 0xF, true));
}
// ds_swizzle BitMode: offset = (xor<<10) | (or<<5) | and ; and=0x1F keeps lane id
template<int OFF>
__device__ __forceinline__ float swzf(float v) {
    return __int_as_float(__builtin_amdgcn_ds_swizzle(__float_as_int(v), OFF));
}
#define SWZ_XOR4  0x101F
#define SWZ_XOR8  0x201F
#define SWZ_XOR16 0x401F

__device__ __forceinline__ float fxor(float v, int s) {
    return __int_as_float(__float_as_int(v) ^ s);
}

// full-wave sum broadcast. Masks {1,2,7,15,16,32} are linearly independent over
// GF(2)^6, so the butterfly still yields the exact full sum in every lane even
// though stages 3/4 are mirrors (lane^7, lane^15) rather than single-bit xors.
__device__ __forceinline__ float wave_bcast_sum(float v) {
    v += dppf<DPP_XOR1>(v);
    v += dppf<DPP_XOR2>(v);
    v += dppf<DPP_MIR7>(v);
    v += dppf<DPP_MIR15>(v);
    v += swzf<SWZ_XOR16>(v);
    v += __shfl_xor(v, 32, 64);
    return v;
}

// EXACT xor-shuffle for quantum wire J (mask = 32 >> J)
template<int J> __device__ __forceinline__ float gsh(float v) {
    if constexpr (J == 0) return __shfl_xor(v, 32, 64);
    else if constexpr (J == 1) return swzf<SWZ_XOR16>(v);
    else if constexpr (J == 2) return swzf<SWZ_XOR8>(v);
    else if constexpr (J == 3) return swzf<SWZ_XOR4>(v);
    else if constexpr (J == 4) return dppf<DPP_XOR2>(v);
    else return dppf<DPP_XOR1>(v);
}

__global__ __launch_bounds__(256) void hybridqrc_kernel(
    const float* __restrict__ xs,  const float* __restrict__ xl,
    const float* __restrict__ csw, const float* __restrict__ csb,
    const float* __restrict__ lsw, const float* __restrict__ lsb,
    const float* __restrict__ clw, const float* __restrict__ clb,
    const float* __restrict__ llw, const float* __restrict__ llb,
    const float* __restrict__ qw,  const float* __restrict__ fc1w,
    const float* __restrict__ fc1b,const float* __restrict__ fc2w,
    const float* __restrict__ fc2b,float* __restrict__ out, int B)
{
    // ---- per-block: 12 Rot gates, pre-selected per target-bit ----
    // gme[gate*2+bit] = (own_r, own_i, oth_r, oth_i)
    __shared__ float4 gme[24];
    const int tid = threadIdx.x;
    if (tid < 24) {
        int g = tid >> 1, bit = tid & 1;
        float phi = qw[g * 3 + 0], th = qw[g * 3 + 1], om = qw[g * 3 + 2];
        float a = 0.5f * (phi + om), b = 0.5f * (phi - om);
        float ca = cosf(a), sa = sinf(a);
        float cb = cosf(b), sb = sinf(b);
        float ct = cosf(0.5f * th), st = sinf(0.5f * th);
        float4 v;
        if (bit) { v.x = ca * ct; v.y =  sa * ct; v.z =  cb * st; v.w = -sb * st; }
        else     { v.x = ca * ct; v.y = -sa * ct; v.z = -cb * st; v.w = -sb * st; }
        gme[tid] = v;
    }
    __syncthreads();

    const int lane = tid & 63;
    const int wave = blockIdx.x * WAVES_PER_BLOCK + (tid >> 6);
    const int base = wave * SPW;
    if (base >= B) return;

    // ---- fused CNOT-ring permutations (lane-only, sample-independent) ----
    int perm0, perm1;
    {
        int y = lane;
#pragma unroll
        for (int j = 5; j >= 0; j--) {
            const int t = (j + 1) % 6;
            y ^= (y & (1 << (5 - j))) ? (1 << (5 - t)) : 0;
        }
        perm0 = y;
        y = lane;
#pragma unroll
        for (int j = 5; j >= 0; j--) {
            const int t = (j + 2) % 6;
            y ^= (y & (1 << (5 - j))) ? (1 << (5 - t)) : 0;
        }
        perm1 = y;
    }
    // per-lane WH sign masks: sg[s] = ((lane>>s)&1) << 31
    int sg[6];
#pragma unroll
    for (int s = 0; s < 6; s++) sg[s] = ((lane >> s) & 1) << 31;

    // ---- classical branches: accumulate combined (short+long) linear sums ----
    float acc[SPW][6];
#pragma unroll
    for (int i = 0; i < SPW; i++)
#pragma unroll
        for (int q = 0; q < 6; q++) acc[i][q] = 0.f;

    // short branch: lane = position w in [0,64)
    float xsv[SPW], xm1[SPW], xp1[SPW];
#pragma unroll
    for (int i = 0; i < SPW; i++) xsv[i] = xs[(base + i) * 64 + lane];
#pragma unroll
    for (int i = 0; i < SPW; i++) {
        float lft = __shfl(xsv[i], (lane + 63) & 63, 64);
        float rgt = __shfl(xsv[i], (lane + 1) & 63, 64);
        xm1[i] = (lane == 0)  ? 0.f : lft;
        xp1[i] = (lane == 63) ? 0.f : rgt;
    }
#pragma unroll
    for (int c = 0; c < 16; c++) {
        float w0 = csw[c * 3 + 0], w1 = csw[c * 3 + 1], w2 = csw[c * 3 + 2];
        float bb = csb[c];
        float h[SPW];
#pragma unroll
        for (int i = 0; i < SPW; i++)
            h[i] = fmaxf(0.f, fmaf(w0, xm1[i], fmaf(w1, xsv[i], fmaf(w2, xp1[i], bb))));
#pragma unroll
        for (int q = 0; q < 6; q++) {
            float wv = lsw[q * 1024 + c * 64 + lane];
#pragma unroll
            for (int i = 0; i < SPW; i++) acc[i][q] = fmaf(h[i], wv, acc[i][q]);
        }
    }

    // long branch: lane owns positions lane*4 .. lane*4+3
    float4 xlv[SPW];
    float l2v[SPW], l1v[SPW], r1v[SPW], r2v[SPW];
#pragma unroll
    for (int i = 0; i < SPW; i++)
        xlv[i] = reinterpret_cast<const float4*>(xl + (size_t)(base + i) * 256)[lane];
#pragma unroll
    for (int i = 0; i < SPW; i++) {
        float a = __shfl(xlv[i].z, (lane + 63) & 63, 64);
        float b = __shfl(xlv[i].w, (lane + 63) & 63, 64);
        float c = __shfl(xlv[i].x, (lane + 1) & 63, 64);
        float d = __shfl(xlv[i].y, (lane + 1) & 63, 64);
        l2v[i] = (lane == 0)  ? 0.f : a;
        l1v[i] = (lane == 0)  ? 0.f : b;
        r1v[i] = (lane == 63) ? 0.f : c;
        r2v[i] = (lane == 63) ? 0.f : d;
    }
#pragma unroll
    for (int c = 0; c < 16; c++) {
        float w0 = clw[c * 5 + 0], w1 = clw[c * 5 + 1], w2 = clw[c * 5 + 2];
        float w3 = clw[c * 5 + 3], w4 = clw[c * 5 + 4];
        float bb = clb[c];
        float p0[SPW], p1[SPW];
#pragma unroll
        for (int i = 0; i < SPW; i++) {
            float vx = xlv[i].x, vy = xlv[i].y, vz = xlv[i].z, vw = xlv[i].w;
            float h0 = fmaf(w0, l2v[i], fmaf(w1, l1v[i], fmaf(w2, vx, fmaf(w3, vy, fmaf(w4, vz, bb)))));
            float h1 = fmaf(w0, l1v[i], fmaf(w1, vx, fmaf(w2, vy, fmaf(w3, vz, fmaf(w4, vw, bb)))));
            float h2 = fmaf(w0, vx, fmaf(w1, vy, fmaf(w2, vz, fmaf(w3, vw, fmaf(w4, r1v[i], bb)))));
            float h3 = fmaf(w0, vy, fmaf(w1, vz, fmaf(w2, vw, fmaf(w3, r1v[i], fmaf(w4, r2v[i], bb)))));
            h0 = fmaxf(h0, 0.f); h1 = fmaxf(h1, 0.f);
            h2 = fmaxf(h2, 0.f); h3 = fmaxf(h3, 0.f);
            p0[i] = fmaxf(h0, h1);
            p1[i] = fmaxf(h2, h3);
        }
#pragma unroll
        for (int q = 0; q < 6; q++) {
            float2 wv = reinterpret_cast<const float2*>(llw + q * 2048 + c * 128)[lane];
#pragma unroll
            for (int i = 0; i < SPW; i++)
                acc[i][q] = fmaf(p0[i], wv.x, fmaf(p1[i], wv.y, acc[i][q]));
        }
    }

    // f = (fs + fl)/2 ; biases added once after the wave reduction
    float f[SPW][6];
#pragma unroll
    for (int i = 0; i < SPW; i++)
#pragma unroll
        for (int q = 0; q < 6; q++)
            f[i][q] = 0.5f * (wave_bcast_sum(acc[i][q]) + lsb[q] + llb[q]);

    // ---- quantum circuit: 64 amplitudes == 64 lanes (wire j <-> bit 5-j) ----
    // encoding: RY(pi*f)|0..0> -> real product state
    float ar[SPW], ai[SPW];
#pragma unroll
    for (int i = 0; i < SPW; i++) { ar[i] = 1.f; ai[i] = 0.f; }
#pragma unroll
    for (int j = 0; j < 6; j++) {
        const int mask = 1 << (5 - j);
#pragma unroll
        for (int i = 0; i < SPW; i++) {
            float th = 1.57079632679489662f * f[i][j];
            float ss = __sinf(th), cc = __cosf(th);
            ar[i] *= (lane & mask) ? ss : cc;
        }
    }

#define APPLY_GATE(L, J) do {                                              \
        const int _mask = 1 << (5 - (J));                                  \
        const int _bit = (lane & _mask) ? 1 : 0;                           \
        float4 g = gme[((L) * 6 + (J)) * 2 + _bit];                        \
        _Pragma("unroll")                                                  \
        for (int i = 0; i < SPW; i++) {                                    \
            float br = gsh<J>(ar[i]);                                      \
            float bi = gsh<J>(ai[i]);                                      \
            float nr = g.x * ar[i] - g.y * ai[i] + g.z * br - g.w * bi;    \
            float ni = g.x * ai[i] + g.y * ar[i] + g.z * bi + g.w * br;    \
            ar[i] = nr; ai[i] = ni;                                        \
        } } while (0)

    APPLY_GATE(0, 0); APPLY_GATE(0, 1); APPLY_GATE(0, 2);
    APPLY_GATE(0, 3); APPLY_GATE(0, 4); APPLY_GATE(0, 5);
#pragma unroll
    for (int i = 0; i < SPW; i++) {
        float pr = __shfl(ar[i], perm0, 64);
        float pi2 = __shfl(ai[i], perm0, 64);
        ar[i] = pr; ai[i] = pi2;
    }
    APPLY_GATE(1, 0); APPLY_GATE(1, 1); APPLY_GATE(1, 2);
    APPLY_GATE(1, 3); APPLY_GATE(1, 4); APPLY_GATE(1, 5);
#pragma unroll
    for (int i = 0; i < SPW; i++) {
        float pr = __shfl(ar[i], perm1, 64);
        float pi2 = __shfl(ai[i], perm1, 64);
        ar[i] = pr; ai[i] = pi2;
    }

    float outv[SPW];
#pragma unroll
    for (int i = 0; i < SPW; i++) {
        // all six <Z_k> via Walsh-Hadamard butterfly (sign-xor form, EXACT
        // single-bit masks matching sg[s]); z[k] lands in lane 32>>k
        float v = ar[i] * ar[i] + ai[i] * ai[i];
        float t;
        t = dppf<DPP_XOR1>(v);     v = t + fxor(v, sg[0]);
        t = dppf<DPP_XOR2>(v);     v = t + fxor(v, sg[1]);
        t = swzf<SWZ_XOR4>(v);     v = t + fxor(v, sg[2]);
        t = swzf<SWZ_XOR8>(v);     v = t + fxor(v, sg[3]);
        t = swzf<SWZ_XOR16>(v);    v = t + fxor(v, sg[4]);
        t = __shfl_xor(v, 32, 64); v = t + fxor(v, sg[5]);
        float z[6];
#pragma unroll
        for (int k = 0; k < 6; k++)
            z[k] = __int_as_float(__builtin_amdgcn_readlane(__float_as_int(v), 32 >> k));
        // fc head (uniform, computed redundantly per lane)
        float o = fc2b[0];
#pragma unroll
        for (int m = 0; m < 8; m++) {
            float h = fc1b[m];
#pragma unroll
            for (int k = 0; k < 6; k++) h = fmaf(fc1w[m * 6 + k], z[k], h);
            h = fmaxf(h, 0.f);
            o = fmaf(fc2w[m], h, o);
        }
        outv[i] = o;
    }

    if (lane == 0) {
#pragma unroll
        for (int i = 0; i < SPW; i++)
            if (base + i < B) out[base + i] = outv[i];
    }
}

extern "C" void kernel_launch(void* const* d_in, const int* in_sizes, int n_in,
                              void* d_out, int out_size, void* d_ws, size_t ws_size,
                              hipStream_t stream) {
    const float* xs   = (const float*)d_in[0];
    const float* xl   = (const float*)d_in[1];
    const float* csw  = (const float*)d_in[2];
    const float* csb  = (const float*)d_in[3];
    const float* lsw  = (const float*)d_in[4];
    const float* lsb  = (const float*)d_in[5];
    const float* clw  = (const float*)d_in[6];
    const float* clb  = (const float*)d_in[7];
    const float* llw  = (const float*)d_in[8];
    const float* llb  = (const float*)d_in[9];
    const float* qw   = (const float*)d_in[10];
    const float* fc1w = (const float*)d_in[11];
    const float* fc1b = (const float*)d_in[12];
    const float* fc2w = (const float*)d_in[13];
    const float* fc2b = (const float*)d_in[14];
    float* out = (float*)d_out;

    const int B = in_sizes[0] / 64;
    const int waves = (B + SPW - 1) / SPW;
    const int blocks = (waves + WAVES_PER_BLOCK - 1) / WAVES_PER_BLOCK;
    hybridqrc_kernel<<<blocks, 256, 0, stream>>>(
        xs, xl, csw, csb, lsw, lsb, clw, clb, llw, llb,
        qw, fc1w, fc1b, fc2w, fc2b, out, B);
}

// Round 5
// 116.946 us; speedup vs baseline: 1.2980x; 1.0579x over previous
//
#include <hip/hip_runtime.h>
#include <math.h>

#define SPW 2          // samples per wave
#define WPB 8          // waves per block -> 512 threads
#define NTHR (WPB * 64)

__global__ __launch_bounds__(NTHR) void hybridqrc_kernel(
    const float* __restrict__ xs,  const float* __restrict__ xl,
    const float* __restrict__ csw, const float* __restrict__ csb,
    const float* __restrict__ lsw, const float* __restrict__ lsb,
    const float* __restrict__ clw, const float* __restrict__ clb,
    const float* __restrict__ llw, const float* __restrict__ llb,
    const float* __restrict__ qw,  const float* __restrict__ fc1w,
    const float* __restrict__ fc1b,const float* __restrict__ fc2w,
    const float* __restrict__ fc2b,float* __restrict__ out, int B)
{
    // ---- LDS: long-branch linear weights (48 KB) + 12 Rot gates ----
    __shared__ float llw_s[12288];
    __shared__ float4 gme[24];   // [gate*2+bit] = (own_r, own_i, oth_r, oth_i)
    const int tid = threadIdx.x;
#pragma unroll
    for (int idx = 0; idx < 3072; idx += NTHR) {
        int k = idx + tid;
        if (k < 3072)
            reinterpret_cast<float4*>(llw_s)[k] =
                reinterpret_cast<const float4*>(llw)[k];
    }
    if (tid < 24) {
        int g = tid >> 1, bit = tid & 1;
        float phi = qw[g * 3 + 0], th = qw[g * 3 + 1], om = qw[g * 3 + 2];
        float a = 0.5f * (phi + om), b = 0.5f * (phi - om);
        float ca = cosf(a), sa = sinf(a);
        float cb = cosf(b), sb = sinf(b);
        float ct = cosf(0.5f * th), st = sinf(0.5f * th);
        float4 v;
        if (bit) { v.x = ca * ct; v.y =  sa * ct; v.z =  cb * st; v.w = -sb * st; }
        else     { v.x = ca * ct; v.y = -sa * ct; v.z = -cb * st; v.w = -sb * st; }
        gme[tid] = v;
    }
    __syncthreads();

    const int lane = tid & 63;
    const int wave = blockIdx.x * WPB + (tid >> 6);
    const int base = wave * SPW;
    if (base >= B) return;

    // ---- fused CNOT-ring permutations (lane-only, sample-independent) ----
    int perm0, perm1;
    {
        int y = lane;
#pragma unroll
        for (int j = 5; j >= 0; j--) {
            const int t = (j + 1) % 6;
            y ^= (y & (1 << (5 - j))) ? (1 << (5 - t)) : 0;
        }
        perm0 = y;
        y = lane;
#pragma unroll
        for (int j = 5; j >= 0; j--) {
            const int t = (j + 2) % 6;
            y ^= (y & (1 << (5 - j))) ? (1 << (5 - t)) : 0;
        }
        perm1 = y;
    }

    // ---- classical branches: accumulate combined (short+long) linear sums ----
    float acc[SPW][6];
#pragma unroll
    for (int i = 0; i < SPW; i++)
#pragma unroll
        for (int q = 0; q < 6; q++) acc[i][q] = 0.f;

    // short branch: lane = position w in [0,64)
    float xsv[SPW], xm1[SPW], xp1[SPW];
#pragma unroll
    for (int i = 0; i < SPW; i++) xsv[i] = xs[(base + i) * 64 + lane];
#pragma unroll
    for (int i = 0; i < SPW; i++) {
        float lft = __shfl(xsv[i], (lane + 63) & 63, 64);
        float rgt = __shfl(xsv[i], (lane + 1) & 63, 64);
        xm1[i] = (lane == 0)  ? 0.f : lft;
        xp1[i] = (lane == 63) ? 0.f : rgt;
    }
#pragma unroll
    for (int c = 0; c < 16; c++) {
        float w0 = csw[c * 3 + 0], w1 = csw[c * 3 + 1], w2 = csw[c * 3 + 2];
        float bb = csb[c];
        float h[SPW];
#pragma unroll
        for (int i = 0; i < SPW; i++)
            h[i] = fmaxf(0.f, fmaf(w0, xm1[i], fmaf(w1, xsv[i], fmaf(w2, xp1[i], bb))));
#pragma unroll
        for (int q = 0; q < 6; q++) {
            float wv = lsw[q * 1024 + c * 64 + lane];
#pragma unroll
            for (int i = 0; i < SPW; i++) acc[i][q] = fmaf(h[i], wv, acc[i][q]);
        }
    }

    // long branch: lane owns positions lane*4 .. lane*4+3
    float4 xlv[SPW];
    float l2v[SPW], l1v[SPW], r1v[SPW], r2v[SPW];
#pragma unroll
    for (int i = 0; i < SPW; i++)
        xlv[i] = reinterpret_cast<const float4*>(xl + (size_t)(base + i) * 256)[lane];
#pragma unroll
    for (int i = 0; i < SPW; i++) {
        float a = __shfl(xlv[i].z, (lane + 63) & 63, 64);
        float b = __shfl(xlv[i].w, (lane + 63) & 63, 64);
        float c = __shfl(xlv[i].x, (lane + 1) & 63, 64);
        float d = __shfl(xlv[i].y, (lane + 1) & 63, 64);
        l2v[i] = (lane == 0)  ? 0.f : a;
        l1v[i] = (lane == 0)  ? 0.f : b;
        r1v[i] = (lane == 63) ? 0.f : c;
        r2v[i] = (lane == 63) ? 0.f : d;
    }
#pragma unroll
    for (int c = 0; c < 16; c++) {
        float w0 = clw[c * 5 + 0], w1 = clw[c * 5 + 1], w2 = clw[c * 5 + 2];
        float w3 = clw[c * 5 + 3], w4 = clw[c * 5 + 4];
        float bb = clb[c];
        float p0[SPW], p1[SPW];
#pragma unroll
        for (int i = 0; i < SPW; i++) {
            float vx = xlv[i].x, vy = xlv[i].y, vz = xlv[i].z, vw = xlv[i].w;
            float h0 = fmaf(w0, l2v[i], fmaf(w1, l1v[i], fmaf(w2, vx, fmaf(w3, vy, fmaf(w4, vz, bb)))));
            float h1 = fmaf(w0, l1v[i], fmaf(w1, vx, fmaf(w2, vy, fmaf(w3, vz, fmaf(w4, vw, bb)))));
            float h2 = fmaf(w0, vx, fmaf(w1, vy, fmaf(w2, vz, fmaf(w3, vw, fmaf(w4, r1v[i], bb)))));
            float h3 = fmaf(w0, vy, fmaf(w1, vz, fmaf(w2, vw, fmaf(w3, r1v[i], fmaf(w4, r2v[i], bb)))));
            h0 = fmaxf(h0, 0.f); h1 = fmaxf(h1, 0.f);
            h2 = fmaxf(h2, 0.f); h3 = fmaxf(h3, 0.f);
            p0[i] = fmaxf(h0, h1);
            p1[i] = fmaxf(h2, h3);
        }
#pragma unroll
        for (int q = 0; q < 6; q++) {
            float2 wv = reinterpret_cast<const float2*>(llw_s + q * 2048 + c * 128)[lane];
#pragma unroll
            for (int i = 0; i < SPW; i++)
                acc[i][q] = fmaf(p0[i], wv.x, fmaf(p1[i], wv.y, acc[i][q]));
        }
    }

    // ---- reduce-scatter fold: 12 wave-sums in 17 shuffles ----
    // v[0..5]=sample0 q0..5, v[6..11]=sample1 q0..5, v[12..15]=0.
    // After stages (mask 1,2,4,8) value j's partial lives on lanes whose low 4
    // bits are bitrev4(j); xor-16/32 finish the sum. All 12 totals end up in
    // distinct lanes of ONE register -> readlane broadcasts (no DS ops).
    float fv[12];
    {
        float v[16];
#pragma unroll
        for (int q = 0; q < 6; q++) { v[q] = acc[0][q]; v[6 + q] = acc[1][q]; }
        v[12] = 0.f; v[13] = 0.f; v[14] = 0.f; v[15] = 0.f;
        // stage mask=1: 16 -> 8
        {
            const bool hi = lane & 1;
#pragma unroll
            for (int j = 0; j < 8; j++) {
                float snd = hi ? v[j] : v[j + 8];
                float rcv = __shfl_xor(snd, 1, 64);
                float kept = hi ? v[j + 8] : v[j];
                v[j] = kept + rcv;
            }
        }
        // stage mask=2: 8 -> 4
        {
            const bool hi = lane & 2;
#pragma unroll
            for (int j = 0; j < 4; j++) {
                float snd = hi ? v[j] : v[j + 4];
                float rcv = __shfl_xor(snd, 2, 64);
                float kept = hi ? v[j + 4] : v[j];
                v[j] = kept + rcv;
            }
        }
        // stage mask=4: 4 -> 2
        {
            const bool hi = lane & 4;
#pragma unroll
            for (int j = 0; j < 2; j++) {
                float snd = hi ? v[j] : v[j + 2];
                float rcv = __shfl_xor(snd, 4, 64);
                float kept = hi ? v[j + 2] : v[j];
                v[j] = kept + rcv;
            }
        }
        // stage mask=8: 2 -> 1
        {
            const bool hi = lane & 8;
            float snd = hi ? v[0] : v[1];
            float rcv = __shfl_xor(snd, 8, 64);
            float kept = hi ? v[1] : v[0];
            v[0] = kept + rcv;
        }
        float r = v[0];
        r += __shfl_xor(r, 16, 64);
        r += __shfl_xor(r, 32, 64);
        // value j -> lane bitrev4(j)
        const int rl[12] = {0, 8, 4, 12, 2, 10, 6, 14, 1, 9, 5, 13};
#pragma unroll
        for (int j = 0; j < 12; j++)
            fv[j] = __int_as_float(
                __builtin_amdgcn_readlane(__float_as_int(r), rl[j]));
    }
    float f[SPW][6];
#pragma unroll
    for (int i = 0; i < SPW; i++)
#pragma unroll
        for (int q = 0; q < 6; q++)
            f[i][q] = 0.5f * (fv[i * 6 + q] + lsb[q] + llb[q]);

    // ---- quantum circuit: 64 amplitudes == 64 lanes (wire j <-> bit 5-j) ----
    float ar[SPW], ai[SPW];
#pragma unroll
    for (int i = 0; i < SPW; i++) { ar[i] = 1.f; ai[i] = 0.f; }
#pragma unroll
    for (int j = 0; j < 6; j++) {
        const int mask = 1 << (5 - j);
#pragma unroll
        for (int i = 0; i < SPW; i++) {
            float th = 1.57079632679489662f * f[i][j];
            float ss = __sinf(th), cc = __cosf(th);
            ar[i] *= (lane & mask) ? ss : cc;
        }
    }

#define APPLY_GATE(L, J) do {                                              \
        const int _mask = 1 << (5 - (J));                                  \
        const int _bit = (lane & _mask) ? 1 : 0;                           \
        float4 g = gme[((L) * 6 + (J)) * 2 + _bit];                        \
        _Pragma("unroll")                                                  \
        for (int i = 0; i < SPW; i++) {                                    \
            float br = __shfl_xor(ar[i], _mask, 64);                       \
            float bi = __shfl_xor(ai[i], _mask, 64);                       \
            float nr = g.x * ar[i] - g.y * ai[i] + g.z * br - g.w * bi;    \
            float ni = g.x * ai[i] + g.y * ar[i] + g.z * bi + g.w * br;    \
            ar[i] = nr; ai[i] = ni;                                        \
        } } while (0)

    APPLY_GATE(0, 0); APPLY_GATE(0, 1); APPLY_GATE(0, 2);
    APPLY_GATE(0, 3); APPLY_GATE(0, 4); APPLY_GATE(0, 5);
#pragma unroll
    for (int i = 0; i < SPW; i++) {
        float pr = __shfl(ar[i], perm0, 64);
        float pi2 = __shfl(ai[i], perm0, 64);
        ar[i] = pr; ai[i] = pi2;
    }
    APPLY_GATE(1, 0); APPLY_GATE(1, 1); APPLY_GATE(1, 2);
    APPLY_GATE(1, 3); APPLY_GATE(1, 4); APPLY_GATE(1, 5);
#pragma unroll
    for (int i = 0; i < SPW; i++) {
        float pr = __shfl(ar[i], perm1, 64);
        float pi2 = __shfl(ai[i], perm1, 64);
        ar[i] = pr; ai[i] = pi2;
    }

    float outv[SPW];
#pragma unroll
    for (int i = 0; i < SPW; i++) {
        // all six <Z_k> via Walsh-Hadamard butterfly; z[k] lands in lane 32>>k
        float v = ar[i] * ar[i] + ai[i] * ai[i];
#pragma unroll
        for (int m = 1; m < 64; m <<= 1) {
            float pp = __shfl_xor(v, m, 64);
            v = (lane & m) ? (pp - v) : (v + pp);
        }
        float z[6];
#pragma unroll
        for (int k = 0; k < 6; k++)
            z[k] = __int_as_float(
                __builtin_amdgcn_readlane(__float_as_int(v), 32 >> k));
        // fc head (uniform, computed redundantly per lane)
        float o = fc2b[0];
#pragma unroll
        for (int m = 0; m < 8; m++) {
            float h = fc1b[m];
#pragma unroll
            for (int k = 0; k < 6; k++) h = fmaf(fc1w[m * 6 + k], z[k], h);
            h = fmaxf(h, 0.f);
            o = fmaf(fc2w[m], h, o);
        }
        outv[i] = o;
    }

    if (lane == 0) {
#pragma unroll
        for (int i = 0; i < SPW; i++)
            if (base + i < B) out[base + i] = outv[i];
    }
}

extern "C" void kernel_launch(void* const* d_in, const int* in_sizes, int n_in,
                              void* d_out, int out_size, void* d_ws, size_t ws_size,
                              hipStream_t stream) {
    const float* xs   = (const float*)d_in[0];
    const float* xl   = (const float*)d_in[1];
    const float* csw  = (const float*)d_in[2];
    const float* csb  = (const float*)d_in[3];
    const float* lsw  = (const float*)d_in[4];
    const float* lsb  = (const float*)d_in[5];
    const float* clw  = (const float*)d_in[6];
    const float* clb  = (const float*)d_in[7];
    const float* llw  = (const float*)d_in[8];
    const float* llb  = (const float*)d_in[9];
    const float* qw   = (const float*)d_in[10];
    const float* fc1w = (const float*)d_in[11];
    const float* fc1b = (const float*)d_in[12];
    const float* fc2w = (const float*)d_in[13];
    const float* fc2b = (const float*)d_in[14];
    float* out = (float*)d_out;

    const int B = in_sizes[0] / 64;
    const int spb = WPB * SPW;                    // samples per block
    const int blocks = (B + spb - 1) / spb;
    hybridqrc_kernel<<<blocks, NTHR, 0, stream>>>(
        xs, xl, csw, csb, lsw, lsb, clw, clb, llw, llb,
        qw, fc1w, fc1b, fc2w, fc2b, out, B);
}